// Round 1
// baseline (14163.034 us; speedup 1.0000x reference)
//
#include <hip/hip_runtime.h>
#include <cstddef>

typedef __attribute__((ext_vector_type(8))) short short8;
typedef __attribute__((ext_vector_type(4))) short short4v;
typedef __attribute__((ext_vector_type(4))) float f32x4;

__device__ __forceinline__ unsigned short f2bf(float f){
  unsigned u = __builtin_bit_cast(unsigned, f);
  u += 0x7FFFu + ((u >> 16) & 1u);          // round-to-nearest-even
  return (unsigned short)(u >> 16);
}
__device__ __forceinline__ float bf2f(unsigned short h){
  unsigned u = ((unsigned)h) << 16;
  return __builtin_bit_cast(float, u);
}
__device__ __forceinline__ float sigf(float x){
  return __builtin_amdgcn_rcpf(1.0f + __builtin_amdgcn_exp2f(-1.4426950408889634f * x));
}
__device__ __forceinline__ float tanhf_(float x){
  return 1.0f - 2.0f * __builtin_amdgcn_rcpf(1.0f + __builtin_amdgcn_exp2f(2.8853900817779268f * x));
}

// inputs [32][1024][256] fp32 -> xbf [t*32+b][256] bf16
__global__ __launch_bounds__(64) void cast_x(const float* __restrict__ in, unsigned short* __restrict__ xb){
  int blk = blockIdx.x;              // b*1024 + t
  int t = blk & 1023, b = blk >> 10;
  int k = threadIdx.x * 4;
  float4 v = *(const float4*)(in + (size_t)blk * 256 + k);
  unsigned lo = f2bf(v.x) | ((unsigned)f2bf(v.y) << 16);
  unsigned hi = f2bf(v.z) | ((unsigned)f2bf(v.w) << 16);
  *(uint2*)(xb + ((size_t)t * 32 + b) * 256 + k) = make_uint2(lo, hi);
}

// Wih (fw,bw) fp32 -> Bw [2048][K] bf16 (row = dir*1024 + gatecol), bias[row] = bih+bhh
__global__ __launch_bounds__(64) void cast_w(const float* __restrict__ Wf, const float* __restrict__ Wb,
    const float* __restrict__ bihf, const float* __restrict__ bhhf,
    const float* __restrict__ bihb, const float* __restrict__ bhhb,
    unsigned short* __restrict__ Bw, float* __restrict__ bias, int K){
  int row = blockIdx.x;              // 0..2047
  int dd = row >> 10, gc = row & 1023;
  const float* src = (dd ? Wb : Wf) + (size_t)gc * K;
  unsigned short* dst = Bw + (size_t)row * K;
  for (int k = threadIdx.x * 4; k < K; k += 256){
    float4 v = *(const float4*)(src + k);
    unsigned lo = f2bf(v.x) | ((unsigned)f2bf(v.y) << 16);
    unsigned hi = f2bf(v.z) | ((unsigned)f2bf(v.w) << 16);
    *(uint2*)(dst + k) = make_uint2(lo, hi);
  }
  if (threadIdx.x == 0)
    bias[row] = dd ? (bihb[gc] + bhhb[gc]) : (bihf[gc] + bhhf[gc]);
}

// C[row=t*32+b][col 0..2047] = A[row][K] @ Bw[col][K]^T + bias[col], stored xg[t][col][b] bf16
__global__ __launch_bounds__(256) void gemm_xg(const unsigned short* __restrict__ A,
    const unsigned short* __restrict__ Bw, const float* __restrict__ bias,
    unsigned short* __restrict__ xg, int K){
  __shared__ __align__(16) unsigned short Al[128 * 64];
  __shared__ __align__(16) unsigned short Bl[128 * 64];
  const int tid = threadIdx.x;
  const int w = tid >> 6, l = tid & 63, q = l >> 4, cl = l & 15;
  const int bm = blockIdx.x >> 4, bn = blockIdx.x & 15;
  const int wm = w & 1, wn = w >> 1;
  f32x4 acc[4][4];
#pragma unroll
  for (int nt = 0; nt < 4; ++nt){
    float bv = bias[bn * 128 + wn * 64 + nt * 16 + cl];
#pragma unroll
    for (int mt = 0; mt < 4; ++mt) acc[mt][nt] = (f32x4){bv, bv, bv, bv};
  }
  const unsigned short* Ab = A + (size_t)(bm * 128) * K;
  const unsigned short* Bb = Bw + (size_t)(bn * 128) * K;
  for (int k0 = 0; k0 < K; k0 += 64){
#pragma unroll
    for (int i = 0; i < 4; ++i){
      int task = tid + i * 256;
      int row = task >> 3, ch = task & 7;
      int sw = ((ch ^ (row & 7)) * 8);
      *(uint4*)(&Al[row * 64 + sw]) = *(const uint4*)(Ab + (size_t)row * K + k0 + ch * 8);
      *(uint4*)(&Bl[row * 64 + sw]) = *(const uint4*)(Bb + (size_t)row * K + k0 + ch * 8);
    }
    __syncthreads();
#pragma unroll
    for (int kt2 = 0; kt2 < 2; ++kt2){
      short8 af[4], bfv[4];
#pragma unroll
      for (int mt = 0; mt < 4; ++mt){
        int row = wm * 64 + mt * 16 + cl;
        af[mt] = *(const short8*)(&Al[row * 64 + (((kt2 * 4 + q) ^ (row & 7)) * 8)]);
      }
#pragma unroll
      for (int nt = 0; nt < 4; ++nt){
        int n = wn * 64 + nt * 16 + cl;
        bfv[nt] = *(const short8*)(&Bl[n * 64 + (((kt2 * 4 + q) ^ (n & 7)) * 8)]);
      }
#pragma unroll
      for (int mt = 0; mt < 4; ++mt)
#pragma unroll
        for (int nt = 0; nt < 4; ++nt)
          acc[mt][nt] = __builtin_amdgcn_mfma_f32_16x16x32_bf16(af[mt], bfv[nt], acc[mt][nt], 0, 0, 0);
    }
    __syncthreads();
  }
#pragma unroll
  for (int mt = 0; mt < 4; ++mt){
    int row = bm * 128 + wm * 64 + mt * 16 + q * 4;
    int tt = row >> 5, bb = row & 31;
#pragma unroll
    for (int nt = 0; nt < 4; ++nt){
      int col = bn * 128 + wn * 64 + nt * 16 + cl;
      f32x4 v = acc[mt][nt];
      unsigned lo = f2bf(v[0]) | ((unsigned)f2bf(v[1]) << 16);
      unsigned hi = f2bf(v[2]) | ((unsigned)f2bf(v[3]) << 16);
      *(uint2*)(xg + ((size_t)tt * 2048 + col) * 32 + bb) = make_uint2(lo, hi);
    }
  }
}

// Recurrent core. Grid = 32 blocks: unit u = blockIdx%8 (dir = u>>2, batch grp = u&3, 8 batches),
// slice s = blockIdx>>3 owns hidden cols [s*64, s*64+64). Whh slice resident in VGPRs as bf16 B-frags.
// Per step: gates = xg + h@Whh^T (MFMA), fp32 cell update, h exchanged via L2 with release/acquire flags.
__global__ __launch_bounds__(256, 1) void lstm_rec(const unsigned short* __restrict__ xg,
    const float* __restrict__ WhhF, const float* __restrict__ WhhB,
    const float* __restrict__ mask, unsigned short* __restrict__ hx, int* __restrict__ flags,
    unsigned short* __restrict__ houts, float* __restrict__ out,
    float* __restrict__ hnout, float* __restrict__ cnout, int layer){
  const int tid = threadIdx.x;
  const int w = tid >> 6, l = tid & 63, q = l >> 4, cl = l & 15;
  const int u = blockIdx.x & 7, s = blockIdx.x >> 3;
  const int d = u >> 2, b0 = (u & 3) * 8;
  const float* __restrict__ Whh = d ? WhhB : WhhF;
  const int jj = s * 64 + w * 16 + cl;     // hidden index 0..255 owned by this lane
  short8 bfrag[4][8];                      // Whh B-fragments: [gate][ktile], 128 VGPRs
#pragma unroll
  for (int gi = 0; gi < 4; ++gi){
    const float* wr = Whh + (size_t)(gi * 256 + jj) * 256 + q * 8;
#pragma unroll
    for (int kt = 0; kt < 8; ++kt){
      float4 x0 = *(const float4*)(wr + kt * 32);
      float4 x1 = *(const float4*)(wr + kt * 32 + 4);
      short8 f;
      f[0] = (short)f2bf(x0.x); f[1] = (short)f2bf(x0.y); f[2] = (short)f2bf(x0.z); f[3] = (short)f2bf(x0.w);
      f[4] = (short)f2bf(x1.x); f[5] = (short)f2bf(x1.y); f[6] = (short)f2bf(x1.z); f[7] = (short)f2bf(x1.w);
      bfrag[gi][kt] = f;
    }
  }
  float cst[4] = {0.f, 0.f, 0.f, 0.f};
  unsigned short* hxu = hx + (size_t)u * 8192;   // [slot(2)][m(16)][k(256)] bf16
  int* flg = flags + u * 4;
  const bool qv = (q < 2);                 // rows 0..7 are real batches
  const int bq = b0 + q * 4;
  for (int t = 0; t < 1024; ++t){
    const int ot = d ? (1023 - t) : t;
    f32x4 acc[4];
    float mv[4];
    if (qv){
#pragma unroll
      for (int gi = 0; gi < 4; ++gi){
        const unsigned short* xp = xg + ((size_t)ot * 2048 + (d * 1024 + gi * 256 + jj)) * 32 + bq;
        short4v xv = *(const short4v*)xp;
        acc[gi] = (f32x4){bf2f((unsigned short)xv[0]), bf2f((unsigned short)xv[1]),
                          bf2f((unsigned short)xv[2]), bf2f((unsigned short)xv[3])};
      }
#pragma unroll
      for (int r = 0; r < 4; ++r) mv[r] = mask[(size_t)(bq + r) * 1024 + ot];
    } else {
#pragma unroll
      for (int gi = 0; gi < 4; ++gi) acc[gi] = (f32x4){0.f, 0.f, 0.f, 0.f};
#pragma unroll
      for (int r = 0; r < 4; ++r) mv[r] = 1.0f;
    }
    if (t > 0){
      const int tw = t - 1;
      if (l < 4){
        while (__hip_atomic_load(&flg[l], __ATOMIC_ACQUIRE, __HIP_MEMORY_SCOPE_AGENT) < tw) { }
      }
      const unsigned short* hp = hxu + (size_t)(tw & 1) * 4096 + cl * 256 + q * 8;
      short8 af[8];
#pragma unroll
      for (int kt = 0; kt < 8; ++kt) af[kt] = *(const short8*)(hp + kt * 32);
#pragma unroll
      for (int kt = 0; kt < 8; ++kt)
#pragma unroll
        for (int gi = 0; gi < 4; ++gi)
          acc[gi] = __builtin_amdgcn_mfma_f32_16x16x32_bf16(af[kt], bfrag[gi][kt], acc[gi], 0, 0, 0);
    }
    float hv[4];
    unsigned short hb[4];
#pragma unroll
    for (int r = 0; r < 4; ++r){
      float ig = sigf(acc[0][r]);
      float fg = sigf(acc[1][r]);
      float gg = tanhf_(acc[2][r]);
      float og = sigf(acc[3][r]);
      float cn = fg * cst[r] + ig * gg;
      float hn = og * tanhf_(cn);
      hn *= mv[r]; cn *= mv[r];
      cst[r] = cn; hv[r] = hn; hb[r] = f2bf(hn);
    }
    if (qv){
      unsigned short* hw = hxu + (size_t)(t & 1) * 4096 + (q * 4) * 256 + jj;
#pragma unroll
      for (int r = 0; r < 4; ++r) hw[r * 256] = hb[r];
      if (layer == 0){
#pragma unroll
        for (int r = 0; r < 4; ++r)
          houts[((size_t)ot * 32 + bq + r) * 512 + d * 256 + jj] = hb[r];
      } else {
#pragma unroll
        for (int r = 0; r < 4; ++r)
          out[((size_t)(bq + r) * 1024 + ot) * 512 + d * 256 + jj] = hv[r];
      }
      if (t == 1023){
#pragma unroll
        for (int r = 0; r < 4; ++r){
          size_t bo = (size_t)(layer * 32 + bq + r) * 512 + d * 256 + jj;
          hnout[bo] = hv[r];
          cnout[bo] = cst[r];
        }
      }
    }
    __threadfence();
    __syncthreads();
    if (tid == 0)
      __hip_atomic_store(&flg[s], t, __ATOMIC_RELEASE, __HIP_MEMORY_SCOPE_AGENT);
  }
}

extern "C" void kernel_launch(void* const* d_in, const int* in_sizes, int n_in,
                              void* d_out, int out_size, void* d_ws, size_t ws_size,
                              hipStream_t stream){
  const float* inputs  = (const float*)d_in[0];
  const float* mask    = (const float*)d_in[1];
  const float* l0f_Wih = (const float*)d_in[2];
  const float* l0f_Whh = (const float*)d_in[3];
  const float* l0f_bih = (const float*)d_in[4];
  const float* l0f_bhh = (const float*)d_in[5];
  const float* l0b_Wih = (const float*)d_in[6];
  const float* l0b_Whh = (const float*)d_in[7];
  const float* l0b_bih = (const float*)d_in[8];
  const float* l0b_bhh = (const float*)d_in[9];
  const float* l1f_Wih = (const float*)d_in[10];
  const float* l1f_Whh = (const float*)d_in[11];
  const float* l1f_bih = (const float*)d_in[12];
  const float* l1f_bhh = (const float*)d_in[13];
  const float* l1b_Wih = (const float*)d_in[14];
  const float* l1b_Whh = (const float*)d_in[15];
  const float* l1b_bih = (const float*)d_in[16];
  const float* l1b_bhh = (const float*)d_in[17];

  char* ws = (char*)d_ws;
  unsigned short* xg   = (unsigned short*)(ws);                 // [1024][2048][32] bf16, 134217728 B
  unsigned short* xbf  = (unsigned short*)(ws + 134217728);     // [32768][256]  bf16, 16777216 B
  unsigned short* hout = (unsigned short*)(ws + 150994944);     // [32768][512]  bf16, 33554432 B
  unsigned short* B0   = (unsigned short*)(ws + 184549376);     // [2048][256]   bf16, 1048576 B
  unsigned short* B1   = (unsigned short*)(ws + 185597952);     // [2048][512]   bf16, 2097152 B
  float* bias0         = (float*)(ws + 187695104);              // [2048] f32
  float* bias1         = (float*)(ws + 187703296);              // [2048] f32
  unsigned short* hx   = (unsigned short*)(ws + 187711488);     // [8][2][16][256] bf16, 131072 B
  int* flags           = (int*)(ws + 187842560);                // [2][8][4] int, 256 B

  float* out   = (float*)d_out;          // [32][1024][512]
  float* hnout = out + 16777216;         // [2][32][512]
  float* cnout = hnout + 32768;          // [2][32][512]

  hipMemsetAsync(flags, 0xFF, 256, stream);
  hipMemsetAsync(hx, 0, 131072, stream);
  cast_x<<<32768, 64, 0, stream>>>(inputs, xbf);
  cast_w<<<2048, 64, 0, stream>>>(l0f_Wih, l0b_Wih, l0f_bih, l0f_bhh, l0b_bih, l0b_bhh, B0, bias0, 256);
  cast_w<<<2048, 64, 0, stream>>>(l1f_Wih, l1b_Wih, l1f_bih, l1f_bhh, l1b_bih, l1b_bhh, B1, bias1, 512);
  gemm_xg<<<4096, 256, 0, stream>>>(xbf, B0, bias0, xg, 256);
  lstm_rec<<<32, 256, 0, stream>>>(xg, l0f_Whh, l0b_Whh, mask, hx, flags, hout, nullptr, hnout, cnout, 0);
  gemm_xg<<<4096, 256, 0, stream>>>(hout, B1, bias1, xg, 512);
  lstm_rec<<<32, 256, 0, stream>>>(xg, l1f_Whh, l1b_Whh, mask, hx, flags + 32, nullptr, out, hnout, cnout, 1);
}

// Round 2
// 7793.720 us; speedup vs baseline: 1.8172x; 1.8172x over previous
//
#include <hip/hip_runtime.h>
#include <cstddef>

typedef __attribute__((ext_vector_type(8))) short short8;
typedef __attribute__((ext_vector_type(4))) short short4v;
typedef __attribute__((ext_vector_type(4))) float f32x4;
typedef __attribute__((ext_vector_type(2))) unsigned long long ull2;

__device__ __forceinline__ unsigned short f2bf(float f){
  unsigned u = __builtin_bit_cast(unsigned, f);
  u += 0x7FFFu + ((u >> 16) & 1u);          // round-to-nearest-even
  return (unsigned short)(u >> 16);
}
__device__ __forceinline__ float bf2f(unsigned short h){
  unsigned u = ((unsigned)h) << 16;
  return __builtin_bit_cast(float, u);
}
__device__ __forceinline__ float sigf(float x){
  return __builtin_amdgcn_rcpf(1.0f + __builtin_amdgcn_exp2f(-1.4426950408889634f * x));
}
__device__ __forceinline__ float tanhf_(float x){
  return 1.0f - 2.0f * __builtin_amdgcn_rcpf(1.0f + __builtin_amdgcn_exp2f(2.8853900817779268f * x));
}

// inputs [32][1024][256] fp32 -> xbf [t*32+b][256] bf16
__global__ __launch_bounds__(64) void cast_x(const float* __restrict__ in, unsigned short* __restrict__ xb){
  int blk = blockIdx.x;              // b*1024 + t
  int t = blk & 1023, b = blk >> 10;
  int k = threadIdx.x * 4;
  float4 v = *(const float4*)(in + (size_t)blk * 256 + k);
  unsigned lo = f2bf(v.x) | ((unsigned)f2bf(v.y) << 16);
  unsigned hi = f2bf(v.z) | ((unsigned)f2bf(v.w) << 16);
  *(uint2*)(xb + ((size_t)t * 32 + b) * 256 + k) = make_uint2(lo, hi);
}

// Wih (fw,bw) fp32 -> Bw [2048][K] bf16 (row = dir*1024 + gatecol), bias[row] = bih+bhh
__global__ __launch_bounds__(64) void cast_w(const float* __restrict__ Wf, const float* __restrict__ Wb,
    const float* __restrict__ bihf, const float* __restrict__ bhhf,
    const float* __restrict__ bihb, const float* __restrict__ bhhb,
    unsigned short* __restrict__ Bw, float* __restrict__ bias, int K){
  int row = blockIdx.x;              // 0..2047
  int dd = row >> 10, gc = row & 1023;
  const float* src = (dd ? Wb : Wf) + (size_t)gc * K;
  unsigned short* dst = Bw + (size_t)row * K;
  for (int k = threadIdx.x * 4; k < K; k += 256){
    float4 v = *(const float4*)(src + k);
    unsigned lo = f2bf(v.x) | ((unsigned)f2bf(v.y) << 16);
    unsigned hi = f2bf(v.z) | ((unsigned)f2bf(v.w) << 16);
    *(uint2*)(dst + k) = make_uint2(lo, hi);
  }
  if (threadIdx.x == 0)
    bias[row] = dd ? (bihb[gc] + bhhb[gc]) : (bihf[gc] + bhhf[gc]);
}

// C[row=t*32+b][col 0..2047] = A[row][K] @ Bw[col][K]^T + bias[col], stored xg[t][col][b] bf16
__global__ __launch_bounds__(256) void gemm_xg(const unsigned short* __restrict__ A,
    const unsigned short* __restrict__ Bw, const float* __restrict__ bias,
    unsigned short* __restrict__ xg, int K){
  __shared__ __align__(16) unsigned short Al[128 * 64];
  __shared__ __align__(16) unsigned short Bl[128 * 64];
  const int tid = threadIdx.x;
  const int w = tid >> 6, l = tid & 63, q = l >> 4, cl = l & 15;
  const int bm = blockIdx.x >> 4, bn = blockIdx.x & 15;
  const int wm = w & 1, wn = w >> 1;
  f32x4 acc[4][4];
#pragma unroll
  for (int nt = 0; nt < 4; ++nt){
    float bv = bias[bn * 128 + wn * 64 + nt * 16 + cl];
#pragma unroll
    for (int mt = 0; mt < 4; ++mt) acc[mt][nt] = (f32x4){bv, bv, bv, bv};
  }
  const unsigned short* Ab = A + (size_t)(bm * 128) * K;
  const unsigned short* Bb = Bw + (size_t)(bn * 128) * K;
  for (int k0 = 0; k0 < K; k0 += 64){
#pragma unroll
    for (int i = 0; i < 4; ++i){
      int task = tid + i * 256;
      int row = task >> 3, ch = task & 7;
      int sw = ((ch ^ (row & 7)) * 8);
      *(uint4*)(&Al[row * 64 + sw]) = *(const uint4*)(Ab + (size_t)row * K + k0 + ch * 8);
      *(uint4*)(&Bl[row * 64 + sw]) = *(const uint4*)(Bb + (size_t)row * K + k0 + ch * 8);
    }
    __syncthreads();
#pragma unroll
    for (int kt2 = 0; kt2 < 2; ++kt2){
      short8 af[4], bfv[4];
#pragma unroll
      for (int mt = 0; mt < 4; ++mt){
        int row = wm * 64 + mt * 16 + cl;
        af[mt] = *(const short8*)(&Al[row * 64 + (((kt2 * 4 + q) ^ (row & 7)) * 8)]);
      }
#pragma unroll
      for (int nt = 0; nt < 4; ++nt){
        int n = wn * 64 + nt * 16 + cl;
        bfv[nt] = *(const short8*)(&Bl[n * 64 + (((kt2 * 4 + q) ^ (n & 7)) * 8)]);
      }
#pragma unroll
      for (int mt = 0; mt < 4; ++mt)
#pragma unroll
        for (int nt = 0; nt < 4; ++nt)
          acc[mt][nt] = __builtin_amdgcn_mfma_f32_16x16x32_bf16(af[mt], bfv[nt], acc[mt][nt], 0, 0, 0);
    }
    __syncthreads();
  }
#pragma unroll
  for (int mt = 0; mt < 4; ++mt){
    int row = bm * 128 + wm * 64 + mt * 16 + q * 4;
    int tt = row >> 5, bb = row & 31;
#pragma unroll
    for (int nt = 0; nt < 4; ++nt){
      int col = bn * 128 + wn * 64 + nt * 16 + cl;
      f32x4 v = acc[mt][nt];
      unsigned lo = f2bf(v[0]) | ((unsigned)f2bf(v[1]) << 16);
      unsigned hi = f2bf(v[2]) | ((unsigned)f2bf(v[3]) << 16);
      *(uint2*)(xg + ((size_t)tt * 2048 + col) * 32 + bb) = make_uint2(lo, hi);
    }
  }
}

// Recurrent core. Grid = 32 blocks: unit u = blockIdx%8 (dir = u>>2, batch grp = u&3, 8 batches),
// slice s = blockIdx>>3 owns hidden cols [s*64, s*64+64). Whh slice resident in VGPRs as bf16 B-frags.
// Cross-block h exchange: ALL communicated words are agent-scope RELAXED atomics (sc1 -> LLC,
// coherent, NO buffer_inv/buffer_wbl2 cache maintenance). Ordering: h-stores -> s_waitcnt vmcnt(0)
// -> __syncthreads -> relaxed flag store. Consumer: relaxed flag poll -> control-dep sc1 h-loads.
// hx layout per unit: [slot(2)][m(16)][kw(128)] uint32 (each word = bf16 pair along k).
__global__ __launch_bounds__(256, 1) void lstm_rec(const unsigned short* __restrict__ xg,
    const float* __restrict__ WhhF, const float* __restrict__ WhhB,
    const float* __restrict__ mask, unsigned* __restrict__ hx, int* __restrict__ flags,
    unsigned short* __restrict__ houts, float* __restrict__ out,
    float* __restrict__ hnout, float* __restrict__ cnout, int layer){
  const int tid = threadIdx.x;
  const int w = tid >> 6, l = tid & 63, q = l >> 4, cl = l & 15;
  const int u = blockIdx.x & 7, s = blockIdx.x >> 3;
  const int d = u >> 2, b0 = (u & 3) * 8;
  const float* __restrict__ Whh = d ? WhhB : WhhF;
  const int jj = s * 64 + w * 16 + cl;     // hidden index 0..255 owned by this lane
  short8 bfrag[4][8];                      // Whh B-fragments: [gate][ktile], 128 VGPRs
#pragma unroll
  for (int gi = 0; gi < 4; ++gi){
    const float* wr = Whh + (size_t)(gi * 256 + jj) * 256 + q * 8;
#pragma unroll
    for (int kt = 0; kt < 8; ++kt){
      float4 x0 = *(const float4*)(wr + kt * 32);
      float4 x1 = *(const float4*)(wr + kt * 32 + 4);
      short8 f;
      f[0] = (short)f2bf(x0.x); f[1] = (short)f2bf(x0.y); f[2] = (short)f2bf(x0.z); f[3] = (short)f2bf(x0.w);
      f[4] = (short)f2bf(x1.x); f[5] = (short)f2bf(x1.y); f[6] = (short)f2bf(x1.z); f[7] = (short)f2bf(x1.w);
      bfrag[gi][kt] = f;
    }
  }
  float cst[4] = {0.f, 0.f, 0.f, 0.f};
  unsigned* hxu = hx + (size_t)u * 4096;   // [slot(2)][m(16)][kw(128)] uint32
  int* flg = flags + u * 4;
  const bool qv = (q < 2);                 // rows 0..7 are real batches
  const int bq = b0 + q * 4;
  for (int t = 0; t < 1024; ++t){
    const int ot = d ? (1023 - t) : t;
    f32x4 acc[4];
    float mv[4];
    if (qv){
#pragma unroll
      for (int gi = 0; gi < 4; ++gi){
        const unsigned short* xp = xg + ((size_t)ot * 2048 + (d * 1024 + gi * 256 + jj)) * 32 + bq;
        short4v xv = *(const short4v*)xp;
        acc[gi] = (f32x4){bf2f((unsigned short)xv[0]), bf2f((unsigned short)xv[1]),
                          bf2f((unsigned short)xv[2]), bf2f((unsigned short)xv[3])};
      }
#pragma unroll
      for (int r = 0; r < 4; ++r) mv[r] = mask[(size_t)(bq + r) * 1024 + ot];
    } else {
#pragma unroll
      for (int gi = 0; gi < 4; ++gi) acc[gi] = (f32x4){0.f, 0.f, 0.f, 0.f};
#pragma unroll
      for (int r = 0; r < 4; ++r) mv[r] = 1.0f;
    }
    if (t > 0){
      const int tw = t - 1;
      if (l < 4){
        while (__hip_atomic_load(&flg[l], __ATOMIC_RELAXED, __HIP_MEMORY_SCOPE_AGENT) < tw) { }
      }
      const unsigned long long* hp =
          (const unsigned long long*)(hxu + (size_t)(tw & 1) * 2048) + cl * 64 + q * 2;
      short8 af[8];
#pragma unroll
      for (int kt = 0; kt < 8; ++kt){
        unsigned long long lo = __hip_atomic_load(hp + kt * 8,     __ATOMIC_RELAXED, __HIP_MEMORY_SCOPE_AGENT);
        unsigned long long hi = __hip_atomic_load(hp + kt * 8 + 1, __ATOMIC_RELAXED, __HIP_MEMORY_SCOPE_AGENT);
        ull2 v; v[0] = lo; v[1] = hi;
        af[kt] = __builtin_bit_cast(short8, v);
      }
#pragma unroll
      for (int kt = 0; kt < 8; ++kt)
#pragma unroll
        for (int gi = 0; gi < 4; ++gi)
          acc[gi] = __builtin_amdgcn_mfma_f32_16x16x32_bf16(af[kt], bfrag[gi][kt], acc[gi], 0, 0, 0);
    }
    float hv[4];
    unsigned short hb[4];
#pragma unroll
    for (int r = 0; r < 4; ++r){
      float ig = sigf(acc[0][r]);
      float fg = sigf(acc[1][r]);
      float gg = tanhf_(acc[2][r]);
      float og = sigf(acc[3][r]);
      float cn = fg * cst[r] + ig * gg;
      float hn = og * tanhf_(cn);
      hn *= mv[r]; cn *= mv[r];
      cst[r] = cn; hv[r] = hn; hb[r] = f2bf(hn);
    }
    if (qv){
      // pack bf16 pairs along k via lane-xor shuffle, store as 32-bit sc1 atomics
      unsigned p01 = (unsigned)hb[0] | ((unsigned)hb[1] << 16);
      unsigned p23 = (unsigned)hb[2] | ((unsigned)hb[3] << 16);
      unsigned o01 = (unsigned)__shfl_xor((int)p01, 1);
      unsigned o23 = (unsigned)__shfl_xor((int)p23, 1);
      unsigned* hw = hxu + (size_t)(t & 1) * 2048 + (size_t)q * 512 + (jj >> 1);
      if ((cl & 1) == 0){
        unsigned w0 = (p01 & 0xFFFFu) | (o01 << 16);
        unsigned w1 = (p01 >> 16) | (o01 & 0xFFFF0000u);
        __hip_atomic_store(hw,       w0, __ATOMIC_RELAXED, __HIP_MEMORY_SCOPE_AGENT);
        __hip_atomic_store(hw + 128, w1, __ATOMIC_RELAXED, __HIP_MEMORY_SCOPE_AGENT);
      } else {
        unsigned w2 = (o23 & 0xFFFFu) | (p23 << 16);
        unsigned w3 = (o23 >> 16) | (p23 & 0xFFFF0000u);
        __hip_atomic_store(hw + 256, w2, __ATOMIC_RELAXED, __HIP_MEMORY_SCOPE_AGENT);
        __hip_atomic_store(hw + 384, w3, __ATOMIC_RELAXED, __HIP_MEMORY_SCOPE_AGENT);
      }
      if (layer == 0){
#pragma unroll
        for (int r = 0; r < 4; ++r)
          houts[((size_t)ot * 32 + bq + r) * 512 + d * 256 + jj] = hb[r];
      } else {
#pragma unroll
        for (int r = 0; r < 4; ++r)
          out[((size_t)(bq + r) * 1024 + ot) * 512 + d * 256 + jj] = hv[r];
      }
      if (t == 1023){
#pragma unroll
        for (int r = 0; r < 4; ++r){
          size_t bo = (size_t)(layer * 32 + bq + r) * 512 + d * 256 + jj;
          hnout[bo] = hv[r];
          cnout[bo] = cst[r];
        }
      }
    }
    asm volatile("s_waitcnt vmcnt(0)" ::: "memory");
    __syncthreads();
    if (tid == 0)
      __hip_atomic_store(&flg[s], t, __ATOMIC_RELAXED, __HIP_MEMORY_SCOPE_AGENT);
  }
}

extern "C" void kernel_launch(void* const* d_in, const int* in_sizes, int n_in,
                              void* d_out, int out_size, void* d_ws, size_t ws_size,
                              hipStream_t stream){
  const float* inputs  = (const float*)d_in[0];
  const float* mask    = (const float*)d_in[1];
  const float* l0f_Wih = (const float*)d_in[2];
  const float* l0f_Whh = (const float*)d_in[3];
  const float* l0f_bih = (const float*)d_in[4];
  const float* l0f_bhh = (const float*)d_in[5];
  const float* l0b_Wih = (const float*)d_in[6];
  const float* l0b_Whh = (const float*)d_in[7];
  const float* l0b_bih = (const float*)d_in[8];
  const float* l0b_bhh = (const float*)d_in[9];
  const float* l1f_Wih = (const float*)d_in[10];
  const float* l1f_Whh = (const float*)d_in[11];
  const float* l1f_bih = (const float*)d_in[12];
  const float* l1f_bhh = (const float*)d_in[13];
  const float* l1b_Wih = (const float*)d_in[14];
  const float* l1b_Whh = (const float*)d_in[15];
  const float* l1b_bih = (const float*)d_in[16];
  const float* l1b_bhh = (const float*)d_in[17];

  char* ws = (char*)d_ws;
  unsigned short* xg   = (unsigned short*)(ws);                 // [1024][2048][32] bf16, 134217728 B
  unsigned short* xbf  = (unsigned short*)(ws + 134217728);     // [32768][256]  bf16, 16777216 B
  unsigned short* hout = (unsigned short*)(ws + 150994944);     // [32768][512]  bf16, 33554432 B
  unsigned short* B0   = (unsigned short*)(ws + 184549376);     // [2048][256]   bf16, 1048576 B
  unsigned short* B1   = (unsigned short*)(ws + 185597952);     // [2048][512]   bf16, 2097152 B
  float* bias0         = (float*)(ws + 187695104);              // [2048] f32
  float* bias1         = (float*)(ws + 187703296);              // [2048] f32
  unsigned* hx         = (unsigned*)(ws + 187711488);           // [8][2][16][128] u32, 131072 B
  int* flags           = (int*)(ws + 187842560);                // [2][8][4] int, 256 B

  float* out   = (float*)d_out;          // [32][1024][512]
  float* hnout = out + 16777216;         // [2][32][512]
  float* cnout = hnout + 32768;          // [2][32][512]

  hipMemsetAsync(flags, 0xFF, 256, stream);
  hipMemsetAsync(hx, 0, 131072, stream);
  cast_x<<<32768, 64, 0, stream>>>(inputs, xbf);
  cast_w<<<2048, 64, 0, stream>>>(l0f_Wih, l0b_Wih, l0f_bih, l0f_bhh, l0b_bih, l0b_bhh, B0, bias0, 256);
  cast_w<<<2048, 64, 0, stream>>>(l1f_Wih, l1b_Wih, l1f_bih, l1f_bhh, l1b_bih, l1b_bhh, B1, bias1, 512);
  gemm_xg<<<4096, 256, 0, stream>>>(xbf, B0, bias0, xg, 256);
  lstm_rec<<<32, 256, 0, stream>>>(xg, l0f_Whh, l0b_Whh, mask, hx, flags, hout, nullptr, hnout, cnout, 0);
  gemm_xg<<<4096, 256, 0, stream>>>(hout, B1, bias1, xg, 512);
  lstm_rec<<<32, 256, 0, stream>>>(xg, l1f_Whh, l1b_Whh, mask, hx, flags + 32, nullptr, out, hnout, cnout, 1);
}

// Round 3
// 4086.882 us; speedup vs baseline: 3.4655x; 1.9070x over previous
//
#include <hip/hip_runtime.h>
#include <cstddef>

typedef __attribute__((ext_vector_type(8))) short short8;
typedef __attribute__((ext_vector_type(4))) short short4v;
typedef __attribute__((ext_vector_type(4))) float f32x4;

__device__ __forceinline__ unsigned short f2bf(float f){
  unsigned u = __builtin_bit_cast(unsigned, f);
  u += 0x7FFFu + ((u >> 16) & 1u);          // round-to-nearest-even
  return (unsigned short)(u >> 16);
}
__device__ __forceinline__ float bf2f(unsigned short h){
  unsigned u = ((unsigned)h) << 16;
  return __builtin_bit_cast(float, u);
}
__device__ __forceinline__ float sigf(float x){
  return __builtin_amdgcn_rcpf(1.0f + __builtin_amdgcn_exp2f(-1.4426950408889634f * x));
}
__device__ __forceinline__ float tanhf_(float x){
  return 1.0f - 2.0f * __builtin_amdgcn_rcpf(1.0f + __builtin_amdgcn_exp2f(2.8853900817779268f * x));
}

// inputs [32][1024][256] fp32 -> xbf [t*32+b][256] bf16
__global__ __launch_bounds__(64) void cast_x(const float* __restrict__ in, unsigned short* __restrict__ xb){
  int blk = blockIdx.x;              // b*1024 + t
  int t = blk & 1023, b = blk >> 10;
  int k = threadIdx.x * 4;
  float4 v = *(const float4*)(in + (size_t)blk * 256 + k);
  unsigned lo = f2bf(v.x) | ((unsigned)f2bf(v.y) << 16);
  unsigned hi = f2bf(v.z) | ((unsigned)f2bf(v.w) << 16);
  *(uint2*)(xb + ((size_t)t * 32 + b) * 256 + k) = make_uint2(lo, hi);
}

// Wih (fw,bw) fp32 -> Bw [2048][K] bf16 (row = dir*1024 + gatecol), bias[row] = bih+bhh
__global__ __launch_bounds__(64) void cast_w(const float* __restrict__ Wf, const float* __restrict__ Wb,
    const float* __restrict__ bihf, const float* __restrict__ bhhf,
    const float* __restrict__ bihb, const float* __restrict__ bhhb,
    unsigned short* __restrict__ Bw, float* __restrict__ bias, int K){
  int row = blockIdx.x;              // 0..2047
  int dd = row >> 10, gc = row & 1023;
  const float* src = (dd ? Wb : Wf) + (size_t)gc * K;
  unsigned short* dst = Bw + (size_t)row * K;
  for (int k = threadIdx.x * 4; k < K; k += 256){
    float4 v = *(const float4*)(src + k);
    unsigned lo = f2bf(v.x) | ((unsigned)f2bf(v.y) << 16);
    unsigned hi = f2bf(v.z) | ((unsigned)f2bf(v.w) << 16);
    *(uint2*)(dst + k) = make_uint2(lo, hi);
  }
  if (threadIdx.x == 0)
    bias[row] = dd ? (bihb[gc] + bhhb[gc]) : (bihf[gc] + bhhf[gc]);
}

// C[row=t*32+b][col 0..2047] = A[row][K] @ Bw[col][K]^T + bias[col], stored xg[t][col][b] bf16
__global__ __launch_bounds__(256) void gemm_xg(const unsigned short* __restrict__ A,
    const unsigned short* __restrict__ Bw, const float* __restrict__ bias,
    unsigned short* __restrict__ xg, int K){
  __shared__ __align__(16) unsigned short Al[128 * 64];
  __shared__ __align__(16) unsigned short Bl[128 * 64];
  const int tid = threadIdx.x;
  const int w = tid >> 6, l = tid & 63, q = l >> 4, cl = l & 15;
  const int bm = blockIdx.x >> 4, bn = blockIdx.x & 15;
  const int wm = w & 1, wn = w >> 1;
  f32x4 acc[4][4];
#pragma unroll
  for (int nt = 0; nt < 4; ++nt){
    float bv = bias[bn * 128 + wn * 64 + nt * 16 + cl];
#pragma unroll
    for (int mt = 0; mt < 4; ++mt) acc[mt][nt] = (f32x4){bv, bv, bv, bv};
  }
  const unsigned short* Ab = A + (size_t)(bm * 128) * K;
  const unsigned short* Bb = Bw + (size_t)(bn * 128) * K;
  for (int k0 = 0; k0 < K; k0 += 64){
#pragma unroll
    for (int i = 0; i < 4; ++i){
      int task = tid + i * 256;
      int row = task >> 3, ch = task & 7;
      int sw = ((ch ^ (row & 7)) * 8);
      *(uint4*)(&Al[row * 64 + sw]) = *(const uint4*)(Ab + (size_t)row * K + k0 + ch * 8);
      *(uint4*)(&Bl[row * 64 + sw]) = *(const uint4*)(Bb + (size_t)row * K + k0 + ch * 8);
    }
    __syncthreads();
#pragma unroll
    for (int kt2 = 0; kt2 < 2; ++kt2){
      short8 af[4], bfv[4];
#pragma unroll
      for (int mt = 0; mt < 4; ++mt){
        int row = wm * 64 + mt * 16 + cl;
        af[mt] = *(const short8*)(&Al[row * 64 + (((kt2 * 4 + q) ^ (row & 7)) * 8)]);
      }
#pragma unroll
      for (int nt = 0; nt < 4; ++nt){
        int n = wn * 64 + nt * 16 + cl;
        bfv[nt] = *(const short8*)(&Bl[n * 64 + (((kt2 * 4 + q) ^ (n & 7)) * 8)]);
      }
#pragma unroll
      for (int mt = 0; mt < 4; ++mt)
#pragma unroll
        for (int nt = 0; nt < 4; ++nt)
          acc[mt][nt] = __builtin_amdgcn_mfma_f32_16x16x32_bf16(af[mt], bfv[nt], acc[mt][nt], 0, 0, 0);
    }
    __syncthreads();
  }
#pragma unroll
  for (int mt = 0; mt < 4; ++mt){
    int row = bm * 128 + wm * 64 + mt * 16 + q * 4;
    int tt = row >> 5, bb = row & 31;
#pragma unroll
    for (int nt = 0; nt < 4; ++nt){
      int col = bn * 128 + wn * 64 + nt * 16 + cl;
      f32x4 v = acc[mt][nt];
      unsigned lo = f2bf(v[0]) | ((unsigned)f2bf(v[1]) << 16);
      unsigned hi = f2bf(v[2]) | ((unsigned)f2bf(v[3]) << 16);
      *(uint2*)(xg + ((size_t)tt * 2048 + col) * 32 + bb) = make_uint2(lo, hi);
    }
  }
}

// Recurrent core, tag-in-data protocol.
// Grid = 32 blocks: unit u = blockIdx%8 (dir = u>>2, batch grp = u&3, 8 batches),
// slice s = blockIdx>>3 owns hidden cols [s*64, s*64+64). Whh slice in VGPRs (bf16 B-frags).
// hx per unit: [slot(2)][row m(8)][k(256)] u32, each u32 = (h_bf16 << 16) | (tag16 = t+1).
// All hx accesses are agent-coherent (sc1) -> serviced at LLC, no cache maintenance ops.
// Consumer: wave w polls k-tiles {w, w+4} (16B sc1 loads + embedded s_waitcnt), verifies all
// 16 tags, relays payload into double-buffered LDS; one __syncthreads; all waves build
// A-frags from LDS and MFMA. No flags, no per-step vmcnt(0) drain, no release fences:
// 2-slot reuse is race-free via the tag-verified dependency chain.
__global__ __launch_bounds__(256, 1) void lstm_rec(const unsigned short* __restrict__ xg,
    const float* __restrict__ WhhF, const float* __restrict__ WhhB,
    const float* __restrict__ mask, unsigned* __restrict__ hx,
    unsigned short* __restrict__ houts, float* __restrict__ out,
    float* __restrict__ hnout, float* __restrict__ cnout, int layer){
  __shared__ __align__(16) unsigned short Abuf[2 * 8 * 8 * 40]; // [par][kt(8)][row(8)][40 shorts, 80B stride]
  __shared__ float maskL[8192];                                 // [t(1024)][row(8)]
  const int tid = threadIdx.x;
  const int w = tid >> 6, l = tid & 63, q = l >> 4, cl = l & 15;
  const int u = blockIdx.x & 7, s = blockIdx.x >> 3;
  const int d = u >> 2, b0 = (u & 3) * 8;
  const float* __restrict__ Whh = d ? WhhB : WhhF;
  const int jj = s * 64 + w * 16 + cl;     // hidden col owned by this lane
  short8 bfrag[4][8];                      // Whh B-fragments: [gate][ktile], 128 VGPRs
#pragma unroll
  for (int gi = 0; gi < 4; ++gi){
    const float* wr = Whh + (size_t)(gi * 256 + jj) * 256 + q * 8;
#pragma unroll
    for (int kt = 0; kt < 8; ++kt){
      float4 x0 = *(const float4*)(wr + kt * 32);
      float4 x1 = *(const float4*)(wr + kt * 32 + 4);
      short8 f;
      f[0] = (short)f2bf(x0.x); f[1] = (short)f2bf(x0.y); f[2] = (short)f2bf(x0.z); f[3] = (short)f2bf(x0.w);
      f[4] = (short)f2bf(x1.x); f[5] = (short)f2bf(x1.y); f[6] = (short)f2bf(x1.z); f[7] = (short)f2bf(x1.w);
      bfrag[gi][kt] = f;
    }
  }
  // mask -> LDS, layout [t][row] for bank-broadcast reads
  for (int idx = tid; idx < 8192; idx += 256){
    int tt = idx >> 3, r = idx & 7;
    maskL[idx] = mask[(size_t)(b0 + r) * 1024 + tt];
  }
  __syncthreads();
  float cst[4] = {0.f, 0.f, 0.f, 0.f};
  unsigned* hxu = hx + (size_t)u * 4096;   // [slot(2)][m(8)][k(256)] u32
  const bool qv = (q < 2);
  const int bq = b0 + q * 4;
  const int row8 = cl & 7;
  for (int t = 0; t < 1024; ++t){
    const int ot = d ? (1023 - t) : t;
    const int par = t & 1;
    f32x4 acc[4];
    if (qv){
#pragma unroll
      for (int gi = 0; gi < 4; ++gi){
        const unsigned short* xp = xg + ((size_t)ot * 2048 + (d * 1024 + gi * 256 + jj)) * 32 + bq;
        short4v xv = *(const short4v*)xp;
        acc[gi] = (f32x4){bf2f((unsigned short)xv[0]), bf2f((unsigned short)xv[1]),
                          bf2f((unsigned short)xv[2]), bf2f((unsigned short)xv[3])};
      }
    } else {
#pragma unroll
      for (int gi = 0; gi < 4; ++gi) acc[gi] = (f32x4){0.f, 0.f, 0.f, 0.f};
    }
    if (t > 0 && cl < 8){
      // poll k-tiles w and w+4: row cl, k-local q*8..q*8+7 each
      const unsigned* base = hxu + (size_t)(par ^ 1) * 2048 + cl * 256 + q * 8;
      const uint4* p0 = (const uint4*)(base + w * 32);
      const uint4* p1 = p0 + 1;
      const uint4* p2 = (const uint4*)(base + (w + 4) * 32);
      const uint4* p3 = p2 + 1;
      const unsigned tagv = (unsigned)t;
      uint4 va, vb, vc, vd;
      while (true){
        asm volatile(
          "global_load_dwordx4 %0, %4, off sc1\n\t"
          "global_load_dwordx4 %1, %5, off sc1\n\t"
          "global_load_dwordx4 %2, %6, off sc1\n\t"
          "global_load_dwordx4 %3, %7, off sc1\n\t"
          "s_waitcnt vmcnt(0)"
          : "=v"(va), "=v"(vb), "=v"(vc), "=v"(vd)
          : "v"(p0), "v"(p1), "v"(p2), "v"(p3)
          : "memory");
        unsigned x = (va.x ^ tagv) | (va.y ^ tagv) | (va.z ^ tagv) | (va.w ^ tagv)
                   | (vb.x ^ tagv) | (vb.y ^ tagv) | (vb.z ^ tagv) | (vb.w ^ tagv)
                   | (vc.x ^ tagv) | (vc.y ^ tagv) | (vc.z ^ tagv) | (vc.w ^ tagv)
                   | (vd.x ^ tagv) | (vd.y ^ tagv) | (vd.z ^ tagv) | (vd.w ^ tagv);
        if (__all((x & 0xFFFFu) == 0u)) break;
      }
      unsigned short* dst = &Abuf[par * 2560 + w * 320 + cl * 40 + q * 8];
      *(uint4*)dst = (uint4){ (va.x >> 16) | (va.y & 0xFFFF0000u), (va.z >> 16) | (va.w & 0xFFFF0000u),
                              (vb.x >> 16) | (vb.y & 0xFFFF0000u), (vb.z >> 16) | (vb.w & 0xFFFF0000u) };
      unsigned short* dst2 = &Abuf[par * 2560 + (w + 4) * 320 + cl * 40 + q * 8];
      *(uint4*)dst2 = (uint4){ (vc.x >> 16) | (vc.y & 0xFFFF0000u), (vc.z >> 16) | (vc.w & 0xFFFF0000u),
                               (vd.x >> 16) | (vd.y & 0xFFFF0000u), (vd.z >> 16) | (vd.w & 0xFFFF0000u) };
    }
    __syncthreads();
    if (t > 0){
      short8 af[8];
#pragma unroll
      for (int kt = 0; kt < 8; ++kt)
        af[kt] = *(const short8*)(&Abuf[par * 2560 + kt * 320 + row8 * 40 + q * 8]);
#pragma unroll
      for (int kt = 0; kt < 8; ++kt)
#pragma unroll
        for (int gi = 0; gi < 4; ++gi)
          acc[gi] = __builtin_amdgcn_mfma_f32_16x16x32_bf16(af[kt], bfrag[gi][kt], acc[gi], 0, 0, 0);
    }
    if (qv){
      float hv[4];
      unsigned short hb[4];
#pragma unroll
      for (int r = 0; r < 4; ++r){
        float mvr = maskL[ot * 8 + q * 4 + r];
        float ig = sigf(acc[0][r]);
        float fg = sigf(acc[1][r]);
        float gg = tanhf_(acc[2][r]);
        float og = sigf(acc[3][r]);
        float cn = fg * cst[r] + ig * gg;
        float hn = og * tanhf_(cn);
        hn *= mvr; cn *= mvr;
        cst[r] = cn; hv[r] = hn; hb[r] = f2bf(hn);
      }
      const unsigned tagn = (unsigned)(t + 1);
      unsigned* sw = hxu + (size_t)par * 2048 + (size_t)(q * 4) * 256 + jj;
#pragma unroll
      for (int r = 0; r < 4; ++r)
        __hip_atomic_store(sw + r * 256, ((unsigned)hb[r] << 16) | tagn,
                           __ATOMIC_RELAXED, __HIP_MEMORY_SCOPE_AGENT);
      if (layer == 0){
#pragma unroll
        for (int r = 0; r < 4; ++r)
          houts[((size_t)ot * 32 + bq + r) * 512 + d * 256 + jj] = hb[r];
      } else {
#pragma unroll
        for (int r = 0; r < 4; ++r)
          out[((size_t)(bq + r) * 1024 + ot) * 512 + d * 256 + jj] = hv[r];
      }
      if (t == 1023){
#pragma unroll
        for (int r = 0; r < 4; ++r){
          size_t bo = (size_t)(layer * 32 + bq + r) * 512 + d * 256 + jj;
          hnout[bo] = hv[r];
          cnout[bo] = cst[r];
        }
      }
    }
  }
}

extern "C" void kernel_launch(void* const* d_in, const int* in_sizes, int n_in,
                              void* d_out, int out_size, void* d_ws, size_t ws_size,
                              hipStream_t stream){
  const float* inputs  = (const float*)d_in[0];
  const float* mask    = (const float*)d_in[1];
  const float* l0f_Wih = (const float*)d_in[2];
  const float* l0f_Whh = (const float*)d_in[3];
  const float* l0f_bih = (const float*)d_in[4];
  const float* l0f_bhh = (const float*)d_in[5];
  const float* l0b_Wih = (const float*)d_in[6];
  const float* l0b_Whh = (const float*)d_in[7];
  const float* l0b_bih = (const float*)d_in[8];
  const float* l0b_bhh = (const float*)d_in[9];
  const float* l1f_Wih = (const float*)d_in[10];
  const float* l1f_Whh = (const float*)d_in[11];
  const float* l1f_bih = (const float*)d_in[12];
  const float* l1f_bhh = (const float*)d_in[13];
  const float* l1b_Wih = (const float*)d_in[14];
  const float* l1b_Whh = (const float*)d_in[15];
  const float* l1b_bih = (const float*)d_in[16];
  const float* l1b_bhh = (const float*)d_in[17];

  char* ws = (char*)d_ws;
  unsigned short* xg   = (unsigned short*)(ws);                 // [1024][2048][32] bf16, 134217728 B
  unsigned short* xbf  = (unsigned short*)(ws + 134217728);     // [32768][256]  bf16, 16777216 B
  unsigned short* hout = (unsigned short*)(ws + 150994944);     // [32768][512]  bf16, 33554432 B
  unsigned short* B0   = (unsigned short*)(ws + 184549376);     // [2048][256]   bf16, 1048576 B
  unsigned short* B1   = (unsigned short*)(ws + 185597952);     // [2048][512]   bf16, 2097152 B
  float* bias0         = (float*)(ws + 187695104);              // [2048] f32
  float* bias1         = (float*)(ws + 187703296);              // [2048] f32
  unsigned* hx         = (unsigned*)(ws + 187711488);           // 2 layers x [8][2][8][256] u32 = 262144 B

  float* out   = (float*)d_out;          // [32][1024][512]
  float* hnout = out + 16777216;         // [2][32][512]
  float* cnout = hnout + 32768;          // [2][32][512]

  hipMemsetAsync(hx, 0, 262144, stream);  // tag16 = 0, never matches tags 1..1024
  cast_x<<<32768, 64, 0, stream>>>(inputs, xbf);
  cast_w<<<2048, 64, 0, stream>>>(l0f_Wih, l0b_Wih, l0f_bih, l0f_bhh, l0b_bih, l0b_bhh, B0, bias0, 256);
  cast_w<<<2048, 64, 0, stream>>>(l1f_Wih, l1b_Wih, l1f_bih, l1f_bhh, l1b_bih, l1b_bhh, B1, bias1, 512);
  gemm_xg<<<4096, 256, 0, stream>>>(xbf, B0, bias0, xg, 256);
  lstm_rec<<<32, 256, 0, stream>>>(xg, l0f_Whh, l0b_Whh, mask, hx, hout, nullptr, hnout, cnout, 0);
  gemm_xg<<<4096, 256, 0, stream>>>(hout, B1, bias1, xg, 512);
  lstm_rec<<<32, 256, 0, stream>>>(xg, l1f_Whh, l1b_Whh, mask, hx + 32768, nullptr, out, hnout, cnout, 1);
}